// Round 13
// baseline (349.886 us; speedup 1.0000x reference)
//
#include <hip/hip_runtime.h>
#include <hip/hip_cooperative_groups.h>
#include <math.h>

namespace cg = cooperative_groups;

// ---- problem geometry ----
#define T_IN    8192
#define T1      8183        // conv1 'valid' output length
#define T2      8174        // conv2 'valid' output length
#define LP      4087        // after MaxPool1d(2)
#define NFLAT   523136      // 128 * 4087
#define NFLAT4  130784      // NFLAT / 4
#define NDIM    10000
#define RSTRIDE 8208        // padded row stride for r1
#define PROW    8192        // pacc row stride (floats)
#define PA_OFF  (64*RSTRIDE)            // pacc: [2][128][PROW] (mega only)
#define F_OFF   (PA_OFF + 2*128*PROW)   // flat[NFLAT]
#define P_OFF   (F_OFF + NFLAT)         // partials[128][32]
#define NCHUNK  32
#define CHUNK4  4087        // float4 per chunk
#define NVB     1024        // virtual blocks per phase

typedef __attribute__((ext_vector_type(4))) float f4;
typedef __attribute__((ext_vector_type(2))) float f2;

// =====================================================================
// Cooperative mega-kernel, grid-stride virtual blocks (works at ANY
// launched grid size <= co-resident capacity). Phases: A conv1 |
// B1 conv2 partials (c-split 2) | B2 combine+pool | C linear | D hdc.
// =====================================================================
__global__ __launch_bounds__(256, 4) void mega(
    const float* __restrict__ sig,  const float* __restrict__ feat,
    const float* __restrict__ w1,   const float* __restrict__ b1,
    const float* __restrict__ w2,   const float* __restrict__ b2,
    const float* __restrict__ lw,   const float* __restrict__ lb,
    const float* __restrict__ hwm,  const float* __restrict__ hb,
    const float* __restrict__ fw,   const float* __restrict__ fb,
    const int* __restrict__ fidx,
    float* __restrict__ ws,         float* __restrict__ out)
{
  cg::grid_group grid = cg::this_grid();
  float* r1       = ws;
  float* pacc     = ws + PA_OFF;
  float* flat     = ws + F_OFF;
  float* partials = ws + P_OFF;

  const int tid  = threadIdx.x;
  const int b    = blockIdx.x;
  const int nb   = gridDim.x;
  const int lane = tid & 63;
  const int wave = tid >> 6;

  __shared__ float4 srow[266];
  __shared__ float  red[4][257];
  __shared__ __align__(16) float ybuf[128];
  __shared__ float  fv[18];

  // ================= Phase A: conv1 (vb = 32 t x 32 ch-pairs) ========
  for (int vb = b; vb < NVB; vb += nb) {
    __syncthreads();                         // srow reuse guard
    const int t0b = (vb & 31) * 256;
    const int c0  = (vb >> 5) * 2;
    for (int idx = tid; idx < 266; idx += 256) {
      int t = t0b + idx;
      float4 v = make_float4(0.f, 0.f, 0.f, 0.f);
      if (t < T_IN) v = ((const float4*)sig)[t];
      srow[idx] = v;
    }
    __syncthreads();
    const int t = t0b + tid;
    float s[40];
#pragma unroll
    for (int k = 0; k < 10; ++k) {
      float4 v = srow[tid + k];
      s[4*k+0] = v.x; s[4*k+1] = v.y; s[4*k+2] = v.z; s[4*k+3] = v.w;
    }
#pragma unroll
    for (int cc = 0; cc < 2; ++cc) {
      const int c = c0 + cc;
      const float* __restrict__ w = w1 + c * 40;   // block-uniform -> s_load
      float a0 = 0.f, a1 = 0.f, a2 = 0.f, a3 = 0.f;
#pragma unroll
      for (int k = 0; k < 10; ++k) {
        a0 = fmaf(s[4*k+0], w[k     ], a0);
        a1 = fmaf(s[4*k+1], w[10 + k], a1);
        a2 = fmaf(s[4*k+2], w[20 + k], a2);
        a3 = fmaf(s[4*k+3], w[30 + k], a3);
      }
      float v = fmaxf((a0 + a1) + (a2 + a3) + b1[c], 0.f);
      if (t < T1) r1[c * RSTRIDE + t] = v;
    }
  }
  grid.sync();

  // ====== Phase B1: conv2 partials (vb = 32 t x 16 o x 2 c-halves) ===
  for (int vb = b; vb < NVB; vb += nb) {
    const int t0b = (vb & 31) * 256;
    const int o0  = __builtin_amdgcn_readfirstlane(((vb >> 5) & 15) * 8 + wave * 2);
    const int cb  = (vb >> 9) * 32;

    float acc[2][4];
#pragma unroll
    for (int a = 0; a < 2; ++a)
#pragma unroll
      for (int q = 0; q < 4; ++q) acc[a][q] = 0.f;

    for (int ci = 0; ci < 32; ++ci) {
      const int c = cb + ci;
      const f4* __restrict__ p = (const f4*)(r1 + c * RSTRIDE + t0b) + lane;
      f4 v0 = p[0];
      f4 v1 = p[1];
      f4 v2 = p[2];
      f4 v3 = p[3];
      float f[16];
      f[0]=v0.x; f[1]=v0.y; f[2]=v0.z; f[3]=v0.w;
      f[4]=v1.x; f[5]=v1.y; f[6]=v1.z; f[7]=v1.w;
      f[8]=v2.x; f[9]=v2.y; f[10]=v2.z; f[11]=v2.w;
      f[12]=v3.x; f[13]=v3.y; f[14]=v3.z; f[15]=v3.w;
#pragma unroll
      for (int oo = 0; oo < 2; ++oo) {
        const float* __restrict__ w = w2 + ((o0 + oo) * 64 + c) * 10; // wave-uniform
#pragma unroll
        for (int k = 0; k < 10; ++k) {
          float wv = w[k];
#pragma unroll
          for (int q = 0; q < 4; ++q)
            acc[oo][q] = fmaf(wv, f[k + q], acc[oo][q]);
        }
      }
    }
#pragma unroll
    for (int oo = 0; oo < 2; ++oo) {
      f4 v; v.x = acc[oo][0]; v.y = acc[oo][1]; v.z = acc[oo][2]; v.w = acc[oo][3];
      *(f4*)(pacc + (size_t)((vb >> 9) * 128 + o0 + oo) * PROW + t0b + lane * 4) = v;
    }
  }
  grid.sync();

  // ========= Phase B2: combine halves + bias + relu + pool ===========
  for (unsigned idx = (unsigned)b * 256u + tid; idx < NFLAT; idx += (unsigned)nb * 256u) {
    const unsigned o = idx / (unsigned)LP;       // magic-mul div
    const unsigned l = idx - o * (unsigned)LP;
    const unsigned t = 2u * l;
    f2 x0 = *(const f2*)(pacc + (size_t)o * PROW + t);
    f2 x1 = *(const f2*)(pacc + (size_t)(128 + o) * PROW + t);
    const float bias = b2[o];
    float aa = (x0.x + x1.x) + bias;
    float bb = (x0.y + x1.y) + bias;
    flat[idx] = fmaxf(fmaxf(aa, bb), 0.f);       // relu-then-pool == pool-then-relu
  }
  grid.sync();

  // ============ Phase C: linear (vb = 32 ch x 32 j-quads) ============
  for (int vb = b; vb < NVB; vb += nb) {
    __syncthreads();                             // red reuse guard
    const int ch = vb & 31;
    const int j0 = (vb >> 5) * 4;
    const f4* __restrict__ fl = (const f4*)flat + (size_t)ch * CHUNK4;

    float r[4];
#pragma unroll
    for (int ph = 0; ph < 2; ++ph) {
      const int j = j0 + 2 * ph;
      const f4* __restrict__ p0 = (const f4*)lw + (size_t)(j + 0) * NFLAT4 + (size_t)ch * CHUNK4;
      const f4* __restrict__ p1 = (const f4*)lw + (size_t)(j + 1) * NFLAT4 + (size_t)ch * CHUNK4;
      f4 a0 = (f4)0.f, a1 = (f4)0.f;
      for (int i = tid; i < CHUNK4; i += 256) {
        f4 x  = fl[i];
        f4 w0 = p0[i];
        f4 w1 = p1[i];
        a0.x = fmaf(x.x, w0.x, a0.x); a0.y = fmaf(x.y, w0.y, a0.y);
        a0.z = fmaf(x.z, w0.z, a0.z); a0.w = fmaf(x.w, w0.w, a0.w);
        a1.x = fmaf(x.x, w1.x, a1.x); a1.y = fmaf(x.y, w1.y, a1.y);
        a1.z = fmaf(x.z, w1.z, a1.z); a1.w = fmaf(x.w, w1.w, a1.w);
      }
      r[2*ph + 0] = (a0.x + a0.y) + (a0.z + a0.w);
      r[2*ph + 1] = (a1.x + a1.y) + (a1.z + a1.w);
    }

#pragma unroll
    for (int j = 0; j < 4; ++j) red[j][tid] = r[j];
    for (int off = 128; off > 0; off >>= 1) {
      __syncthreads();
      if (tid < off) {
#pragma unroll
        for (int j = 0; j < 4; ++j) red[j][tid] += red[j][tid + off];
      }
    }
    if (tid == 0) {
#pragma unroll
      for (int j = 0; j < 4; ++j) partials[(j0 + j) * NCHUNK + ch] = red[j][0];
    }
  }
  grid.sync();

  // ============ Phase D: hdc finalize (vb = 0..39) ===================
  for (int vb = b; vb < 40; vb += nb) {
    __syncthreads();                             // ybuf/fv reuse guard
    if (tid < 128) {
      float s = lb[tid];
      const float* p = partials + tid * NCHUNK;
#pragma unroll
      for (int c = 0; c < NCHUNK; ++c) s += p[c];
      ybuf[tid] = fmaxf(s, 0.f);
    }
    if (tid < 18) fv[tid] = feat[fidx[tid]];
    __syncthreads();

    const int d = vb * 256 + tid;
    if (d < NDIM) {
      const float4* __restrict__ hwp = (const float4*)(hwm + d * 128);
      const float4* __restrict__ yy  = (const float4*)ybuf;
      float4 ac = make_float4(0, 0, 0, 0);
#pragma unroll
      for (int q = 0; q < 32; ++q) {
        float4 w = hwp[q];
        float4 v = yy[q];
        ac.x = fmaf(w.x, v.x, ac.x); ac.y = fmaf(w.y, v.y, ac.y);
        ac.z = fmaf(w.z, v.z, ac.z); ac.w = fmaf(w.w, v.w, ac.w);
      }
      const float proj = (ac.x + ac.y) + (ac.z + ac.w);
      const float sample_hv = cosf(proj + hb[d]) * sinf(proj);

      float h[18];
#pragma unroll
      for (int i = 0; i < 18; ++i) {
        float fp = fv[i] * fw[i * NDIM + d];
        h[i] = cosf(fp + fb[i * NDIM + d]) * sinf(fp);
      }
      const float feat_hv =
          (h[14] + h[11]) * h[16]
        * (h[4] + h[8] + h[6] + h[1] + h[5] + h[12] + h[17])
        * h[13] * (h[15] + h[2]) * h[3]
        * h[0] * h[10] * h[7] * h[9];

      const float comb = sample_hv + feat_hv;
      out[d] = comb > 0.f ? 1.f : -1.f;
    }
  }
}

// =====================================================================
// FALLBACK: round-11 4-kernel path (known-good 95.4 us), used when the
// cooperative launch is rejected by the runtime.
// =====================================================================
__global__ __launch_bounds__(256) void k1_conv1(
    const float* __restrict__ sig, const float* __restrict__ w1,
    const float* __restrict__ b1, float* __restrict__ r1)
{
  __shared__ float4 srow[266];
  const int tid = threadIdx.x;
  const int t0b = blockIdx.x * 256;
  for (int idx = tid; idx < 266; idx += 256) {
    int t = t0b + idx;
    float4 v = make_float4(0.f, 0.f, 0.f, 0.f);
    if (t < T_IN) v = ((const float4*)sig)[t];
    srow[idx] = v;
  }
  __syncthreads();
  const int t = t0b + tid;
  float s[40];
#pragma unroll
  for (int k = 0; k < 10; ++k) {
    float4 v = srow[tid + k];
    s[4*k+0] = v.x; s[4*k+1] = v.y; s[4*k+2] = v.z; s[4*k+3] = v.w;
  }
  const int c0 = blockIdx.y * 8;
  for (int c = c0; c < c0 + 8; ++c) {
    const float* __restrict__ w = w1 + c * 40;
    float a0 = 0.f, a1 = 0.f, a2 = 0.f, a3 = 0.f;
#pragma unroll
    for (int k = 0; k < 10; ++k) {
      a0 = fmaf(s[4*k+0], w[k     ], a0);
      a1 = fmaf(s[4*k+1], w[10 + k], a1);
      a2 = fmaf(s[4*k+2], w[20 + k], a2);
      a3 = fmaf(s[4*k+3], w[30 + k], a3);
    }
    float v = fmaxf((a0 + a1) + (a2 + a3) + b1[c], 0.f);
    if (t < T1) r1[c * RSTRIDE + t] = v;
  }
}

__global__ __launch_bounds__(256) void k2_conv2pool(
    const float* __restrict__ r1, const float* __restrict__ w2,
    const float* __restrict__ b2, float* __restrict__ flat)
{
  const int tid  = threadIdx.x;
  const int lane = tid & 63;
  const int wave = tid >> 6;
  const int t0b  = blockIdx.x * 256;
  const int o0   = __builtin_amdgcn_readfirstlane(blockIdx.y * 8 + wave * 2);
  const int t0   = t0b + lane * 4;

  float acc[2][4];
#pragma unroll
  for (int a = 0; a < 2; ++a)
#pragma unroll
    for (int q = 0; q < 4; ++q) acc[a][q] = 0.f;

  for (int c = 0; c < 64; ++c) {
    const f4* __restrict__ p = (const f4*)(r1 + c * RSTRIDE + t0b) + lane;
    f4 v0 = p[0];
    f4 v1 = p[1];
    f4 v2 = p[2];
    f4 v3 = p[3];
    float f[16];
    f[0]=v0.x; f[1]=v0.y; f[2]=v0.z; f[3]=v0.w;
    f[4]=v1.x; f[5]=v1.y; f[6]=v1.z; f[7]=v1.w;
    f[8]=v2.x; f[9]=v2.y; f[10]=v2.z; f[11]=v2.w;
    f[12]=v3.x; f[13]=v3.y; f[14]=v3.z; f[15]=v3.w;
#pragma unroll
    for (int oo = 0; oo < 2; ++oo) {
      const float* __restrict__ w = w2 + ((o0 + oo) * 64 + c) * 10;
#pragma unroll
      for (int k = 0; k < 10; ++k) {
        float wv = w[k];
#pragma unroll
        for (int tt = 0; tt < 4; ++tt)
          acc[oo][tt] = fmaf(wv, f[k + tt], acc[oo][tt]);
      }
    }
  }

#pragma unroll
  for (int oo = 0; oo < 2; ++oo) {
    const int o = o0 + oo;
    const float bias = b2[o];
#pragma unroll
    for (int lt = 0; lt < 2; ++lt) {
      float a = acc[oo][2*lt]     + bias;
      float bq = acc[oo][2*lt + 1] + bias;
      float m = fmaxf(fmaxf(a, bq), 0.f);
      int l = t0 / 2 + lt;
      if (l < LP) flat[o * LP + l] = m;
    }
  }
}

__global__ __launch_bounds__(256) void k3_linear(
    const float* __restrict__ lw, const float* __restrict__ flat,
    float* __restrict__ partials)
{
  const int tid = threadIdx.x;
  const int ch  = blockIdx.x;
  const int j0  = blockIdx.y * 4;
  const f4* __restrict__ fl = (const f4*)flat + (size_t)ch * CHUNK4;

  float r[4];
#pragma unroll
  for (int ph = 0; ph < 2; ++ph) {
    const int j = j0 + 2 * ph;
    const f4* __restrict__ p0 = (const f4*)lw + (size_t)(j + 0) * NFLAT4 + (size_t)ch * CHUNK4;
    const f4* __restrict__ p1 = (const f4*)lw + (size_t)(j + 1) * NFLAT4 + (size_t)ch * CHUNK4;
    f4 a0 = (f4)0.f, a1 = (f4)0.f;
    for (int i = tid; i < CHUNK4; i += 256) {
      f4 x  = fl[i];
      f4 w0 = p0[i];
      f4 w1 = p1[i];
      a0.x = fmaf(x.x, w0.x, a0.x); a0.y = fmaf(x.y, w0.y, a0.y);
      a0.z = fmaf(x.z, w0.z, a0.z); a0.w = fmaf(x.w, w0.w, a0.w);
      a1.x = fmaf(x.x, w1.x, a1.x); a1.y = fmaf(x.y, w1.y, a1.y);
      a1.z = fmaf(x.z, w1.z, a1.z); a1.w = fmaf(x.w, w1.w, a1.w);
    }
    r[2*ph + 0] = (a0.x + a0.y) + (a0.z + a0.w);
    r[2*ph + 1] = (a1.x + a1.y) + (a1.z + a1.w);
  }

  __shared__ float red[4][257];
#pragma unroll
  for (int j = 0; j < 4; ++j) red[j][tid] = r[j];
  for (int off = 128; off > 0; off >>= 1) {
    __syncthreads();
    if (tid < off) {
#pragma unroll
      for (int j = 0; j < 4; ++j) red[j][tid] += red[j][tid + off];
    }
  }
  if (tid == 0) {
#pragma unroll
    for (int j = 0; j < 4; ++j) partials[(j0 + j) * NCHUNK + ch] = red[j][0];
  }
}

__global__ __launch_bounds__(64) void k4_hdc(
    const float* __restrict__ partials, const float* __restrict__ lin_b,
    const float* __restrict__ hdc_w, const float* __restrict__ hdc_b,
    const float* __restrict__ feat, const int* __restrict__ feat_idx,
    const float* __restrict__ feat_w, const float* __restrict__ feat_b,
    float* __restrict__ out)
{
  __shared__ __align__(16) float y[128];
  __shared__ float fv[18];
  const int tid = threadIdx.x;
#pragma unroll
  for (int half = 0; half < 2; ++half) {
    const int row = tid + half * 64;
    float s = lin_b[row];
    const float* p = partials + row * NCHUNK;
#pragma unroll
    for (int c = 0; c < NCHUNK; ++c) s += p[c];
    y[row] = fmaxf(s, 0.f);
  }
  if (tid < 18) fv[tid] = feat[feat_idx[tid]];
  __syncthreads();

  const int d = blockIdx.x * 64 + tid;
  if (d >= NDIM) return;

  const float4* __restrict__ hw = (const float4*)(hdc_w + d * 128);
  const float4* __restrict__ yy = (const float4*)y;
  float4 ac = make_float4(0, 0, 0, 0);
#pragma unroll
  for (int q = 0; q < 32; ++q) {
    float4 w = hw[q];
    float4 v = yy[q];
    ac.x = fmaf(w.x, v.x, ac.x); ac.y = fmaf(w.y, v.y, ac.y);
    ac.z = fmaf(w.z, v.z, ac.z); ac.w = fmaf(w.w, v.w, ac.w);
  }
  const float proj = (ac.x + ac.y) + (ac.z + ac.w);
  const float sample_hv = cosf(proj + hdc_b[d]) * sinf(proj);

  float h[18];
#pragma unroll
  for (int i = 0; i < 18; ++i) {
    float fp = fv[i] * feat_w[i * NDIM + d];
    h[i] = cosf(fp + feat_b[i * NDIM + d]) * sinf(fp);
  }
  const float feat_hv =
      (h[14] + h[11]) * h[16]
    * (h[4] + h[8] + h[6] + h[1] + h[5] + h[12] + h[17])
    * h[13] * (h[15] + h[2]) * h[3]
    * h[0] * h[10] * h[7] * h[9];

  const float comb = sample_hv + feat_hv;
  out[d] = comb > 0.f ? 1.f : -1.f;
}

// =====================================================================
extern "C" void kernel_launch(void* const* d_in, const int* in_sizes, int n_in,
                              void* d_out, int out_size, void* d_ws, size_t ws_size,
                              hipStream_t stream)
{
  const float* sig  = (const float*)d_in[0];
  const float* feat = (const float*)d_in[1];
  const float* w1   = (const float*)d_in[2];
  const float* b1   = (const float*)d_in[3];
  const float* w2   = (const float*)d_in[4];
  const float* b2   = (const float*)d_in[5];
  const float* lw   = (const float*)d_in[6];
  const float* lb   = (const float*)d_in[7];
  const float* hw   = (const float*)d_in[8];
  const float* hb   = (const float*)d_in[9];
  const float* fw   = (const float*)d_in[10];
  const float* fb   = (const float*)d_in[11];
  const int*   fidx = (const int*)d_in[12];
  float* out = (float*)d_out;
  float* ws  = (float*)d_ws;

  // Size the cooperative grid from the runtime's own occupancy model.
  int nblk = 0;
  hipError_t oe = hipOccupancyMaxActiveBlocksPerMultiprocessor(
      &nblk, (const void*)mega, 256, 0);
  int gsz = NVB;
  if (oe == hipSuccess && nblk > 0) {
    long cap = (long)nblk * 256;   // 256 CUs on MI355X
    if (cap < gsz) gsz = (int)cap;
  }

  void* args[] = { (void*)&sig, (void*)&feat, (void*)&w1, (void*)&b1,
                   (void*)&w2,  (void*)&b2,   (void*)&lw, (void*)&lb,
                   (void*)&hw,  (void*)&hb,   (void*)&fw, (void*)&fb,
                   (void*)&fidx, (void*)&ws,  (void*)&out };
  hipError_t err = hipLaunchCooperativeKernel((const void*)mega, dim3(gsz),
                                              dim3(256), args, 0, stream);
  if (err != hipSuccess) {
    (void)hipGetLastError();       // clear sticky error; use fallback path
    float* r1       = ws;
    float* flat     = ws + F_OFF;
    float* partials = ws + P_OFF;
    k1_conv1    <<<dim3(32, 8),  256, 0, stream>>>(sig, w1, b1, r1);
    k2_conv2pool<<<dim3(32, 16), 256, 0, stream>>>(r1, w2, b2, flat);
    k3_linear   <<<dim3(32, 32), 256, 0, stream>>>(lw, flat, partials);
    k4_hdc      <<<dim3(157, 1), 64,  0, stream>>>(partials, lb, hw, hb,
                                                   feat, fidx, fw, fb, out);
  }
}

// Round 14
// 99.694 us; speedup vs baseline: 3.5096x; 3.5096x over previous
//
#include <hip/hip_runtime.h>
#include <math.h>

// ---- problem geometry ----
#define T_IN    8192
#define T1      8183        // conv1 'valid' output length
#define LP      4087        // after MaxPool1d(2)
#define NFLAT   523136      // 128 * 4087
#define NFLAT4  130784      // NFLAT / 4
#define NDIM    10000
#define RSTRIDE 8208        // padded row stride for r1
#define F_OFF   (64*RSTRIDE)     // start of flat[] in ws (floats)
#define P_OFF   (F_OFF + NFLAT)  // start of partials[128][32] in ws
#define G_OFF   (P_OFF + 8192)   // gap-probe scratch
#define NCHUNK  32
#define CHUNK4  4087        // float4 per chunk

typedef __attribute__((ext_vector_type(4))) float f4;

// =====================================================================
// Kernel 1: conv1 (round-11 exact)
// =====================================================================
__global__ __launch_bounds__(256) void k1_conv1(
    const float* __restrict__ sig, const float* __restrict__ w1,
    const float* __restrict__ b1, float* __restrict__ r1)
{
  __shared__ float4 srow[266];
  const int tid = threadIdx.x;
  const int t0b = blockIdx.x * 256;
  for (int idx = tid; idx < 266; idx += 256) {
    int t = t0b + idx;
    float4 v = make_float4(0.f, 0.f, 0.f, 0.f);
    if (t < T_IN) v = ((const float4*)sig)[t];
    srow[idx] = v;
  }
  __syncthreads();
  const int t = t0b + tid;
  float s[40];
#pragma unroll
  for (int k = 0; k < 10; ++k) {
    float4 v = srow[tid + k];
    s[4*k+0] = v.x; s[4*k+1] = v.y; s[4*k+2] = v.z; s[4*k+3] = v.w;
  }
  const int c0 = blockIdx.y * 8;
  for (int c = c0; c < c0 + 8; ++c) {
    const float* __restrict__ w = w1 + c * 40;
    float a0 = 0.f, a1 = 0.f, a2 = 0.f, a3 = 0.f;
#pragma unroll
    for (int k = 0; k < 10; ++k) {
      a0 = fmaf(s[4*k+0], w[k     ], a0);
      a1 = fmaf(s[4*k+1], w[10 + k], a1);
      a2 = fmaf(s[4*k+2], w[20 + k], a2);
      a3 = fmaf(s[4*k+3], w[30 + k], a3);
    }
    float v = fmaxf((a0 + a1) + (a2 + a3) + b1[c], 0.f);
    if (t < T1) r1[c * RSTRIDE + t] = v;
  }
}

// =====================================================================
// Kernel 2: conv2+pool, LDS-free, 2 ch/wave (round-11 exact)
// =====================================================================
__global__ __launch_bounds__(256) void k2_conv2pool(
    const float* __restrict__ r1, const float* __restrict__ w2,
    const float* __restrict__ b2, float* __restrict__ flat)
{
  const int tid  = threadIdx.x;
  const int lane = tid & 63;
  const int wave = tid >> 6;
  const int t0b  = blockIdx.x * 256;
  const int o0   = __builtin_amdgcn_readfirstlane(blockIdx.y * 8 + wave * 2);
  const int t0   = t0b + lane * 4;

  float acc[2][4];
#pragma unroll
  for (int a = 0; a < 2; ++a)
#pragma unroll
    for (int q = 0; q < 4; ++q) acc[a][q] = 0.f;

  for (int c = 0; c < 64; ++c) {
    const f4* __restrict__ p = (const f4*)(r1 + c * RSTRIDE + t0b) + lane;
    f4 v0 = p[0];
    f4 v1 = p[1];
    f4 v2 = p[2];
    f4 v3 = p[3];
    float f[16];
    f[0]=v0.x; f[1]=v0.y; f[2]=v0.z; f[3]=v0.w;
    f[4]=v1.x; f[5]=v1.y; f[6]=v1.z; f[7]=v1.w;
    f[8]=v2.x; f[9]=v2.y; f[10]=v2.z; f[11]=v2.w;
    f[12]=v3.x; f[13]=v3.y; f[14]=v3.z; f[15]=v3.w;
#pragma unroll
    for (int oo = 0; oo < 2; ++oo) {
      const float* __restrict__ w = w2 + ((o0 + oo) * 64 + c) * 10; // wave-uniform s_loads
#pragma unroll
      for (int k = 0; k < 10; ++k) {
        float wv = w[k];
#pragma unroll
        for (int tt = 0; tt < 4; ++tt)
          acc[oo][tt] = fmaf(wv, f[k + tt], acc[oo][tt]);
      }
    }
  }

#pragma unroll
  for (int oo = 0; oo < 2; ++oo) {
    const int o = o0 + oo;
    const float bias = b2[o];
#pragma unroll
    for (int lt = 0; lt < 2; ++lt) {
      float a = acc[oo][2*lt]     + bias;
      float b = acc[oo][2*lt + 1] + bias;
      float m = fmaxf(fmaxf(a, b), 0.f);      // relu then pool == pool then relu
      int l = t0 / 2 + lt;
      if (l < LP) flat[o * LP + l] = m;
    }
  }
}

// =====================================================================
// Kernel 3: linear, plain loads (round-11 exact; 37.5 us, ~50% MALL hit)
// =====================================================================
__global__ __launch_bounds__(256) void k3_linear(
    const float* __restrict__ lw, const float* __restrict__ flat,
    float* __restrict__ partials)
{
  const int tid = threadIdx.x;
  const int ch  = blockIdx.x;
  const int j0  = blockIdx.y * 4;
  const f4* __restrict__ fl = (const f4*)flat + (size_t)ch * CHUNK4;

  float r[4];
#pragma unroll
  for (int ph = 0; ph < 2; ++ph) {
    const int j = j0 + 2 * ph;
    const f4* __restrict__ p0 = (const f4*)lw + (size_t)(j + 0) * NFLAT4 + (size_t)ch * CHUNK4;
    const f4* __restrict__ p1 = (const f4*)lw + (size_t)(j + 1) * NFLAT4 + (size_t)ch * CHUNK4;
    f4 a0 = (f4)0.f, a1 = (f4)0.f;
    for (int i = tid; i < CHUNK4; i += 256) {
      f4 x  = fl[i];
      f4 w0 = p0[i];
      f4 w1 = p1[i];
      a0.x = fmaf(x.x, w0.x, a0.x); a0.y = fmaf(x.y, w0.y, a0.y);
      a0.z = fmaf(x.z, w0.z, a0.z); a0.w = fmaf(x.w, w0.w, a0.w);
      a1.x = fmaf(x.x, w1.x, a1.x); a1.y = fmaf(x.y, w1.y, a1.y);
      a1.z = fmaf(x.z, w1.z, a1.z); a1.w = fmaf(x.w, w1.w, a1.w);
    }
    r[2*ph + 0] = (a0.x + a0.y) + (a0.z + a0.w);
    r[2*ph + 1] = (a1.x + a1.y) + (a1.z + a1.w);
  }

  __shared__ float red[4][257];
#pragma unroll
  for (int j = 0; j < 4; ++j) red[j][tid] = r[j];
  for (int off = 128; off > 0; off >>= 1) {
    __syncthreads();
    if (tid < off) {
#pragma unroll
      for (int j = 0; j < 4; ++j) red[j][tid] += red[j][tid + off];
    }
  }
  if (tid == 0) {
#pragma unroll
    for (int j = 0; j < 4; ++j) partials[(j0 + j) * NCHUNK + ch] = red[j][0];
  }
}

// =====================================================================
// GAP PROBES: near-zero-work kernels. Three extra dispatch boundaries
// between k3 and k4 -> total_dur = 95.4 + 3*gap + ~1. Writes go to
// unused ws scratch (deterministic, output-invisible).
// =====================================================================
__global__ __launch_bounds__(64) void k_gap(float* __restrict__ g, int slot)
{
  if (threadIdx.x == 0) g[slot] = 1.0f;
}

// =====================================================================
// Kernel 4: finalize (round-11 exact)
// =====================================================================
__global__ __launch_bounds__(64) void k4_hdc(
    const float* __restrict__ partials, const float* __restrict__ lin_b,
    const float* __restrict__ hdc_w, const float* __restrict__ hdc_b,
    const float* __restrict__ feat, const int* __restrict__ feat_idx,
    const float* __restrict__ feat_w, const float* __restrict__ feat_b,
    float* __restrict__ out)
{
  __shared__ __align__(16) float y[128];
  __shared__ float fv[18];
  const int tid = threadIdx.x;
#pragma unroll
  for (int half = 0; half < 2; ++half) {
    const int row = tid + half * 64;
    float s = lin_b[row];
    const float* p = partials + row * NCHUNK;
#pragma unroll
    for (int c = 0; c < NCHUNK; ++c) s += p[c];
    y[row] = fmaxf(s, 0.f);
  }
  if (tid < 18) fv[tid] = feat[feat_idx[tid]];
  __syncthreads();

  const int d = blockIdx.x * 64 + tid;
  if (d >= NDIM) return;

  const float4* __restrict__ hw = (const float4*)(hdc_w + d * 128);
  const float4* __restrict__ yy = (const float4*)y;
  float4 ac = make_float4(0, 0, 0, 0);
#pragma unroll
  for (int q = 0; q < 32; ++q) {
    float4 w = hw[q];
    float4 v = yy[q];
    ac.x = fmaf(w.x, v.x, ac.x); ac.y = fmaf(w.y, v.y, ac.y);
    ac.z = fmaf(w.z, v.z, ac.z); ac.w = fmaf(w.w, v.w, ac.w);
  }
  const float proj = (ac.x + ac.y) + (ac.z + ac.w);
  const float sample_hv = cosf(proj + hdc_b[d]) * sinf(proj);

  float h[18];
#pragma unroll
  for (int i = 0; i < 18; ++i) {
    float fp = fv[i] * feat_w[i * NDIM + d];
    h[i] = cosf(fp + feat_b[i * NDIM + d]) * sinf(fp);
  }
  const float feat_hv =
      (h[14] + h[11]) * h[16]
    * (h[4] + h[8] + h[6] + h[1] + h[5] + h[12] + h[17])
    * h[13] * (h[15] + h[2]) * h[3]
    * h[0] * h[10] * h[7] * h[9];

  const float comb = sample_hv + feat_hv;
  out[d] = comb > 0.f ? 1.f : -1.f;
}

// =====================================================================
extern "C" void kernel_launch(void* const* d_in, const int* in_sizes, int n_in,
                              void* d_out, int out_size, void* d_ws, size_t ws_size,
                              hipStream_t stream)
{
  const float* sig  = (const float*)d_in[0];
  const float* feat = (const float*)d_in[1];
  const float* w1   = (const float*)d_in[2];
  const float* b1   = (const float*)d_in[3];
  const float* w2   = (const float*)d_in[4];
  const float* b2   = (const float*)d_in[5];
  const float* lw   = (const float*)d_in[6];
  const float* lb   = (const float*)d_in[7];
  const float* hw   = (const float*)d_in[8];
  const float* hb   = (const float*)d_in[9];
  const float* fw   = (const float*)d_in[10];
  const float* fb   = (const float*)d_in[11];
  const int*   fidx = (const int*)d_in[12];
  float* out = (float*)d_out;
  float* ws  = (float*)d_ws;

  float* r1       = ws;              // [64][RSTRIDE]
  float* flat     = ws + F_OFF;      // [NFLAT]
  float* partials = ws + P_OFF;      // [128][NCHUNK]
  float* gscratch = ws + G_OFF;      // gap-probe scratch

  k1_conv1    <<<dim3(32, 8),  256, 0, stream>>>(sig, w1, b1, r1);
  k2_conv2pool<<<dim3(32, 16), 256, 0, stream>>>(r1, w2, b2, flat);
  k3_linear   <<<dim3(32, 32), 256, 0, stream>>>(lw, flat, partials);
  k_gap       <<<dim3(1),      64,  0, stream>>>(gscratch, 0);
  k_gap       <<<dim3(1),      64,  0, stream>>>(gscratch, 1);
  k_gap       <<<dim3(1),      64,  0, stream>>>(gscratch, 2);
  k4_hdc      <<<dim3(157, 1), 64,  0, stream>>>(partials, lb, hw, hb,
                                                 feat, fidx, fw, fb, out);
}

// Round 15
// 88.258 us; speedup vs baseline: 3.9644x; 1.1296x over previous
//
#include <hip/hip_runtime.h>
#include <math.h>

// ---- problem geometry ----
#define T_IN    8192
#define T1      8183        // conv1 'valid' output length
#define LP      4087        // after MaxPool1d(2)
#define NFLAT   523136      // 128 * 4087
#define NFLAT4  130784      // NFLAT / 4
#define NDIM    10000
#define RSTRIDE 8208        // padded row stride for r1
#define PROW    8192        // pacc row stride
#define PA_OFF  (64*RSTRIDE)            // pacc: [2][128][PROW]
#define F_OFF   (PA_OFF + 2*128*PROW)   // flat[NFLAT]
#define P_OFF   (F_OFF + NFLAT)         // partials[128][32]
#define NCHUNK  32
#define CHUNK4  4087        // float4 per chunk

typedef __attribute__((ext_vector_type(4))) float f4;
typedef __attribute__((ext_vector_type(2))) float f2;

// =====================================================================
// Kernel 1: conv1 (round-11 exact; ~2 us)
// =====================================================================
__global__ __launch_bounds__(256) void k1_conv1(
    const float* __restrict__ sig, const float* __restrict__ w1,
    const float* __restrict__ b1, float* __restrict__ r1)
{
  __shared__ float4 srow[266];
  const int tid = threadIdx.x;
  const int t0b = blockIdx.x * 256;
  for (int idx = tid; idx < 266; idx += 256) {
    int t = t0b + idx;
    float4 v = make_float4(0.f, 0.f, 0.f, 0.f);
    if (t < T_IN) v = ((const float4*)sig)[t];
    srow[idx] = v;
  }
  __syncthreads();
  const int t = t0b + tid;
  float s[40];
#pragma unroll
  for (int k = 0; k < 10; ++k) {
    float4 v = srow[tid + k];
    s[4*k+0] = v.x; s[4*k+1] = v.y; s[4*k+2] = v.z; s[4*k+3] = v.w;
  }
  const int c0 = blockIdx.y * 8;
  for (int c = c0; c < c0 + 8; ++c) {
    const float* __restrict__ w = w1 + c * 40;
    float a0 = 0.f, a1 = 0.f, a2 = 0.f, a3 = 0.f;
#pragma unroll
    for (int k = 0; k < 10; ++k) {
      a0 = fmaf(s[4*k+0], w[k     ], a0);
      a1 = fmaf(s[4*k+1], w[10 + k], a1);
      a2 = fmaf(s[4*k+2], w[20 + k], a2);
      a3 = fmaf(s[4*k+3], w[30 + k], a3);
    }
    float v = fmaxf((a0 + a1) + (a2 + a3) + b1[c], 0.f);
    if (t < T1) r1[c * RSTRIDE + t] = v;
  }
}

// =====================================================================
// Kernel 2a: conv2 partials, input-channel split x2.
// grid (32 t, 16 o-octets, 2 c-halves) = 1024 blocks = 4/CU: 2x the
// waves of round-11's k2 to hide cold r1/w2 first-touch latency, with
// UNCHANGED load:FMA ratio (round-10's 1ch/wave wash showed ratio
// matters). #pragma unroll 2 -> 8 outstanding window loads per wave.
// Writes pacc[half][o][t] (combined in k2b).
// =====================================================================
__global__ __launch_bounds__(256) void k2a_conv2part(
    const float* __restrict__ r1, const float* __restrict__ w2,
    float* __restrict__ pacc)
{
  const int tid  = threadIdx.x;
  const int lane = tid & 63;
  const int wave = tid >> 6;
  const int t0b  = blockIdx.x * 256;
  const int o0   = __builtin_amdgcn_readfirstlane(blockIdx.y * 8 + wave * 2);
  const int h    = blockIdx.z;             // c-half
  const int cb   = h * 32;

  float acc[2][4];
#pragma unroll
  for (int a = 0; a < 2; ++a)
#pragma unroll
    for (int q = 0; q < 4; ++q) acc[a][q] = 0.f;

#pragma unroll 2
  for (int ci = 0; ci < 32; ++ci) {
    const int c = cb + ci;
    const f4* __restrict__ p = (const f4*)(r1 + c * RSTRIDE + t0b) + lane;
    f4 v0 = p[0];          // floats t0 .. t0+3   (consecutive lanes coalesced)
    f4 v1 = p[1];
    f4 v2 = p[2];
    f4 v3 = p[3];          // f[13..15] dead; stays inside padded row
    float f[16];
    f[0]=v0.x; f[1]=v0.y; f[2]=v0.z; f[3]=v0.w;
    f[4]=v1.x; f[5]=v1.y; f[6]=v1.z; f[7]=v1.w;
    f[8]=v2.x; f[9]=v2.y; f[10]=v2.z; f[11]=v2.w;
    f[12]=v3.x; f[13]=v3.y; f[14]=v3.z; f[15]=v3.w;
#pragma unroll
    for (int oo = 0; oo < 2; ++oo) {
      const float* __restrict__ w = w2 + ((o0 + oo) * 64 + c) * 10; // wave-uniform s_loads
#pragma unroll
      for (int k = 0; k < 10; ++k) {
        float wv = w[k];
#pragma unroll
        for (int tt = 0; tt < 4; ++tt)
          acc[oo][tt] = fmaf(wv, f[k + tt], acc[oo][tt]);
      }
    }
  }

#pragma unroll
  for (int oo = 0; oo < 2; ++oo) {
    f4 v; v.x = acc[oo][0]; v.y = acc[oo][1]; v.z = acc[oo][2]; v.w = acc[oo][3];
    *(f4*)(pacc + (size_t)(h * 128 + o0 + oo) * PROW + t0b + lane * 4) = v;
  }
}

// =====================================================================
// Kernel 2b: combine halves + bias + relu + pool -> flat.
// (round-13 mega phase B2, standalone; ~2.5 us: 8.4 MB fresh read +
// 2 MB write, all L2/MALL-resident.)
// =====================================================================
__global__ __launch_bounds__(256) void k2b_combine(
    const float* __restrict__ pacc, const float* __restrict__ b2,
    float* __restrict__ flat)
{
  const unsigned gtid = blockIdx.x * 256u + threadIdx.x;
#pragma unroll
  for (int e = 0; e < 2; ++e) {
    const unsigned idx = gtid + e * 262144u;
    if (idx < NFLAT) {
      const unsigned o = idx / (unsigned)LP;     // magic-mul div
      const unsigned l = idx - o * (unsigned)LP;
      const unsigned t = 2u * l;
      f2 x0 = *(const f2*)(pacc + (size_t)o * PROW + t);
      f2 x1 = *(const f2*)(pacc + (size_t)(128 + o) * PROW + t);
      const float bias = b2[o];
      float aa = (x0.x + x1.x) + bias;
      float bb = (x0.y + x1.y) + bias;
      flat[idx] = fmaxf(fmaxf(aa, bb), 0.f);     // relu-then-pool == pool-then-relu
    }
  }
}

// =====================================================================
// Kernel 3: linear, plain loads (round-11 exact; 37.5 us, ~50% MALL hit)
// =====================================================================
__global__ __launch_bounds__(256) void k3_linear(
    const float* __restrict__ lw, const float* __restrict__ flat,
    float* __restrict__ partials)
{
  const int tid = threadIdx.x;
  const int ch  = blockIdx.x;
  const int j0  = blockIdx.y * 4;
  const f4* __restrict__ fl = (const f4*)flat + (size_t)ch * CHUNK4;

  float r[4];
#pragma unroll
  for (int ph = 0; ph < 2; ++ph) {
    const int j = j0 + 2 * ph;
    const f4* __restrict__ p0 = (const f4*)lw + (size_t)(j + 0) * NFLAT4 + (size_t)ch * CHUNK4;
    const f4* __restrict__ p1 = (const f4*)lw + (size_t)(j + 1) * NFLAT4 + (size_t)ch * CHUNK4;
    f4 a0 = (f4)0.f, a1 = (f4)0.f;
    for (int i = tid; i < CHUNK4; i += 256) {
      f4 x  = fl[i];
      f4 w0 = p0[i];
      f4 w1 = p1[i];
      a0.x = fmaf(x.x, w0.x, a0.x); a0.y = fmaf(x.y, w0.y, a0.y);
      a0.z = fmaf(x.z, w0.z, a0.z); a0.w = fmaf(x.w, w0.w, a0.w);
      a1.x = fmaf(x.x, w1.x, a1.x); a1.y = fmaf(x.y, w1.y, a1.y);
      a1.z = fmaf(x.z, w1.z, a1.z); a1.w = fmaf(x.w, w1.w, a1.w);
    }
    r[2*ph + 0] = (a0.x + a0.y) + (a0.z + a0.w);
    r[2*ph + 1] = (a1.x + a1.y) + (a1.z + a1.w);
  }

  __shared__ float red[4][257];
#pragma unroll
  for (int j = 0; j < 4; ++j) red[j][tid] = r[j];
  for (int off = 128; off > 0; off >>= 1) {
    __syncthreads();
    if (tid < off) {
#pragma unroll
      for (int j = 0; j < 4; ++j) red[j][tid] += red[j][tid + off];
    }
  }
  if (tid == 0) {
#pragma unroll
    for (int j = 0; j < 4; ++j) partials[(j0 + j) * NCHUNK + ch] = red[j][0];
  }
}

// =====================================================================
// Kernel 4: finalize (round-11 exact; ~3.7 us)
// =====================================================================
__global__ __launch_bounds__(64) void k4_hdc(
    const float* __restrict__ partials, const float* __restrict__ lin_b,
    const float* __restrict__ hdc_w, const float* __restrict__ hdc_b,
    const float* __restrict__ feat, const int* __restrict__ feat_idx,
    const float* __restrict__ feat_w, const float* __restrict__ feat_b,
    float* __restrict__ out)
{
  __shared__ __align__(16) float y[128];
  __shared__ float fv[18];
  const int tid = threadIdx.x;
#pragma unroll
  for (int half = 0; half < 2; ++half) {
    const int row = tid + half * 64;
    float s = lin_b[row];
    const float* p = partials + row * NCHUNK;
#pragma unroll
    for (int c = 0; c < NCHUNK; ++c) s += p[c];
    y[row] = fmaxf(s, 0.f);
  }
  if (tid < 18) fv[tid] = feat[feat_idx[tid]];
  __syncthreads();

  const int d = blockIdx.x * 64 + tid;
  if (d >= NDIM) return;

  const float4* __restrict__ hw = (const float4*)(hdc_w + d * 128);
  const float4* __restrict__ yy = (const float4*)y;
  float4 ac = make_float4(0, 0, 0, 0);
#pragma unroll
  for (int q = 0; q < 32; ++q) {
    float4 w = hw[q];
    float4 v = yy[q];
    ac.x = fmaf(w.x, v.x, ac.x); ac.y = fmaf(w.y, v.y, ac.y);
    ac.z = fmaf(w.z, v.z, ac.z); ac.w = fmaf(w.w, v.w, ac.w);
  }
  const float proj = (ac.x + ac.y) + (ac.z + ac.w);
  const float sample_hv = cosf(proj + hdc_b[d]) * sinf(proj);

  float h[18];
#pragma unroll
  for (int i = 0; i < 18; ++i) {
    float fp = fv[i] * feat_w[i * NDIM + d];
    h[i] = cosf(fp + feat_b[i * NDIM + d]) * sinf(fp);
  }
  const float feat_hv =
      (h[14] + h[11]) * h[16]
    * (h[4] + h[8] + h[6] + h[1] + h[5] + h[12] + h[17])
    * h[13] * (h[15] + h[2]) * h[3]
    * h[0] * h[10] * h[7] * h[9];

  const float comb = sample_hv + feat_hv;
  out[d] = comb > 0.f ? 1.f : -1.f;
}

// =====================================================================
extern "C" void kernel_launch(void* const* d_in, const int* in_sizes, int n_in,
                              void* d_out, int out_size, void* d_ws, size_t ws_size,
                              hipStream_t stream)
{
  const float* sig  = (const float*)d_in[0];
  const float* feat = (const float*)d_in[1];
  const float* w1   = (const float*)d_in[2];
  const float* b1   = (const float*)d_in[3];
  const float* w2   = (const float*)d_in[4];
  const float* b2   = (const float*)d_in[5];
  const float* lw   = (const float*)d_in[6];
  const float* lb   = (const float*)d_in[7];
  const float* hw   = (const float*)d_in[8];
  const float* hb   = (const float*)d_in[9];
  const float* fw   = (const float*)d_in[10];
  const float* fb   = (const float*)d_in[11];
  const int*   fidx = (const int*)d_in[12];
  float* out = (float*)d_out;
  float* ws  = (float*)d_ws;

  float* r1       = ws;              // [64][RSTRIDE]
  float* pacc     = ws + PA_OFF;     // [2][128][PROW]
  float* flat     = ws + F_OFF;      // [NFLAT]
  float* partials = ws + P_OFF;      // [128][NCHUNK]

  k1_conv1    <<<dim3(32, 8),     256, 0, stream>>>(sig, w1, b1, r1);
  k2a_conv2part<<<dim3(32, 16, 2), 256, 0, stream>>>(r1, w2, pacc);
  k2b_combine <<<dim3(1024),      256, 0, stream>>>(pacc, b2, flat);
  k3_linear   <<<dim3(32, 32),    256, 0, stream>>>(lw, flat, partials);
  k4_hdc      <<<dim3(157, 1),    64,  0, stream>>>(partials, lb, hw, hb,
                                                    feat, fidx, fw, fb, out);
}